// Round 4
// baseline (106.099 us; speedup 1.0000x reference)
//
#include <hip/hip_runtime.h>
#include <cstdint>

#define N_NODES 8192
#define DIN 128
#define DOUT 128
#define MAXDEG 128                               // Poisson(32): P(deg>128) ~ 1e-18
#define EPS 1e-8f

#define MB_ROWS 64                               // adjacency rows per build block
#define MB_BLOCKS (N_NODES / MB_ROWS)            // 128
#define WPR (N_NODES / 32)                       // 256 u32 words per adjacency row
#define XW_ROWS 64                               // rows per xw block
#define XW_BLOCKS (N_NODES / XW_ROWS)            // 128

// workspace layout (bytes): [dis 32KB][deg 32KB][list(u16) 2MB][z16 2MB]
#define OFF_DEG  (N_NODES * 4)
#define OFF_LIST (OFF_DEG + N_NODES * 4)
#define OFF_Z16  (OFF_LIST + N_NODES * MAXDEG * 2)

static __device__ __forceinline__ uint16_t f2bf(float f) {
    uint32_t u = __float_as_uint(f);
    return (uint16_t)((u + 0x7fffu + ((u >> 16) & 1u)) >> 16);   // RNE
}
static __device__ __forceinline__ float bf2f(uint32_t bits16) {
    return __uint_as_float(bits16 << 16);
}

// ---------------------------------------------------------------------------
// Kernel 1 (fused): blocks [0,128): adjacency build + extract, entirely in LDS.
//   Block b owns rows [b*64, b*64+64) as a 64 KB LDS bitmask. Streams src+dst
//   as coalesced int4 in chunks of 4 pairs (16 edges/thread), double-buffered
//   in two named register sets.
//   __launch_bounds__(512, 1): LDS already caps us at 1 block/CU (2 waves/
//   SIMD), so let the compiler use up to 256 VGPRs — the A/B chunk buffers
//   need 64 VGPRs live to actually pipeline (round-3 build had VGPR=68 and
//   the double-buffer was serialized).
// blocks [128,256): z16 = bf16(x @ W^T), 64 rows per block (4 column-teams).
// ---------------------------------------------------------------------------
__global__ __launch_bounds__(512, 1) void gcn_build(const int* __restrict__ ei, int E,
                                                 const float* __restrict__ x,
                                                 const float* __restrict__ W,
                                                 uint16_t* __restrict__ z16,
                                                 float* __restrict__ dis,
                                                 int* __restrict__ deg,
                                                 uint16_t* __restrict__ list) {
    __shared__ uint32_t shbuf[MB_ROWS * WPR];    // 64 KB (xw role reuses 32 KB as float)
    int t = threadIdx.x;

    if ((int)blockIdx.x < MB_BLOCKS) {
        // ---------------- adjacency-slice role ----------------
        int mb = blockIdx.x;
        int r0 = mb * MB_ROWS;
        uint32_t (*lm)[WPR] = (uint32_t(*)[WPR])shbuf;

        // init: zero with the diagonal (self-loop) bit folded in -> no race
        int diag_base = mb * 2;
        for (int w4 = t; w4 < MB_ROWS * WPR / 4; w4 += 512) {
            uint32_t w0 = w4 * 4;
            uint32_t vals[4];
#pragma unroll
            for (int k = 0; k < 4; k++) {
                uint32_t w = w0 + k;
                uint32_t r = w >> 8;
                uint32_t wir = w & 255u;
                vals[k] = (wir == (uint32_t)(diag_base + (int)(r >> 5)))
                              ? (1u << ((r0 + r) & 31)) : 0u;
            }
            ((uint4*)shbuf)[w4] = make_uint4(vals[0], vals[1], vals[2], vals[3]);
        }
        __syncthreads();

        // ---- edge stream: chunks of 4 int4-pairs, A/B register double-buffer
        const int4* s4 = (const int4*)ei;
        const int4* d4 = (const int4*)(ei + E);
        int nIter  = E >> 2;                     // int4 groups
        int nChunk = nIter >> 11;                // 4*512 groups per chunk

#define LOADC(S0,S1,S2,S3,D0,D1,D2,D3,c) do { int b_ = ((c) << 11) + t;       \
            S0 = s4[b_];        S1 = s4[b_ + 512];                             \
            S2 = s4[b_ + 1024]; S3 = s4[b_ + 1536];                            \
            D0 = d4[b_];        D1 = d4[b_ + 512];                             \
            D2 = d4[b_ + 1024]; D3 = d4[b_ + 1536]; } while (0)

#define PROC1(cs, cd) do { unsigned r_;                                        \
            r_ = (unsigned)(cs.x - r0);                                        \
            if (r_ < MB_ROWS) atomicOr(&lm[r_][cd.x >> 5], 1u << (cd.x & 31)); \
            r_ = (unsigned)(cs.y - r0);                                        \
            if (r_ < MB_ROWS) atomicOr(&lm[r_][cd.y >> 5], 1u << (cd.y & 31)); \
            r_ = (unsigned)(cs.z - r0);                                        \
            if (r_ < MB_ROWS) atomicOr(&lm[r_][cd.z >> 5], 1u << (cd.z & 31)); \
            r_ = (unsigned)(cs.w - r0);                                        \
            if (r_ < MB_ROWS) atomicOr(&lm[r_][cd.w >> 5], 1u << (cd.w & 31)); } while (0)

        int4 as0, as1, as2, as3, ad0, ad1, ad2, ad3;
        int4 bs0, bs1, bs2, bs3, bd0, bd1, bd2, bd3;

        if (nChunk > 0) LOADC(as0,as1,as2,as3, ad0,ad1,ad2,ad3, 0);
        for (int c = 0; c < nChunk; c += 2) {
            if (c + 1 < nChunk) LOADC(bs0,bs1,bs2,bs3, bd0,bd1,bd2,bd3, c + 1);
            PROC1(as0, ad0); PROC1(as1, ad1); PROC1(as2, ad2); PROC1(as3, ad3);
            if (c + 2 < nChunk) LOADC(as0,as1,as2,as3, ad0,ad1,ad2,ad3, c + 2);
            if (c + 1 < nChunk) {
                PROC1(bs0, bd0); PROC1(bs1, bd1); PROC1(bs2, bd2); PROC1(bs3, bd3);
            }
        }
        // remainder int4 groups (none at E=262144, kept for generality)
        for (int i4 = (nChunk << 11) + t; i4 < nIter; i4 += 512) {
            int4 cs = s4[i4], cd = d4[i4];
            PROC1(cs, cd);
        }
        // scalar tail (E % 4)
        int rem = E & 3;
        if (t < rem) {
            int base = E & ~3;
            int s = ei[base + t], dd = ei[E + base + t];
            unsigned r = (unsigned)(s - r0);
            if (r < MB_ROWS) atomicOr(&lm[r][dd >> 5], 1u << (dd & 31));
        }
#undef LOADC
#undef PROC1
        __syncthreads();

        // extract: wave per row, 8 rows per wave. popcount + wave prefix scan
        int wave = t >> 6, lane = t & 63;
        for (int rr = 0; rr < MB_ROWS / 8; rr++) {
            int r = wave * (MB_ROWS / 8) + rr;
            int row = r0 + r;
            uint4 w = ((const uint4*)lm[r])[lane];   // words 4*lane .. 4*lane+3
            uint32_t wa[4] = {w.x, w.y, w.z, w.w};
            int c = __popc(w.x) + __popc(w.y) + __popc(w.z) + __popc(w.w);

            int sum = c;                             // inclusive wave scan (width 64)
            for (int off = 1; off < 64; off <<= 1) {
                int v = __shfl_up(sum, off, 64);
                if (lane >= off) sum += v;
            }
            int excl = sum - c;
            if (lane == 63) {
                deg[row] = sum;
                dis[row] = rsqrtf((float)sum + EPS);
            }

            uint16_t* lrow = list + (size_t)row * MAXDEG;
            int bbase = lane * 128;                  // first bit index of this lane
            int pos = excl;
#pragma unroll
            for (int k = 0; k < 4; k++) {
                uint32_t m = wa[k];
                while (m) {
                    int b = __ffs(m) - 1;
                    m &= m - 1;
                    if (pos < MAXDEG) lrow[pos] = (uint16_t)(bbase + k * 32 + b);
                    pos++;
                }
            }
        }
        return;
    }

    // ---------------- xw role: 4 column-teams of 128; team h does 16 rows ----
    int bb = blockIdx.x - MB_BLOCKS;
    int col = t & 127;
    int team = t >> 7;                               // 0..3
    int row0 = bb * XW_ROWS + team * 16;
    float (*xl)[DIN] = (float(*)[DIN])shbuf;         // 32 KB of the 64 KB buffer

    for (int rr = 0; rr < 16; rr++)
        xl[team * 16 + rr][col] = x[(size_t)(row0 + rr) * DIN + col];
    __syncthreads();

    float acc[16];
#pragma unroll
    for (int rr = 0; rr < 16; rr++) acc[rr] = 0.f;

    const float* wrow = W + (size_t)col * DIN;
    for (int d = 0; d < DIN; d += 4) {
        float4 wv = *(const float4*)(wrow + d);
#pragma unroll
        for (int rr = 0; rr < 16; rr++) {
            const float* xr = &xl[team * 16 + rr][d];   // wave-uniform b128 broadcast
            acc[rr] += xr[0] * wv.x + xr[1] * wv.y + xr[2] * wv.z + xr[3] * wv.w;
        }
    }
#pragma unroll
    for (int rr = 0; rr < 16; rr++)
        z16[(size_t)(row0 + rr) * DOUT + col] = f2bf(acc[rr]);
}

// ---------------------------------------------------------------------------
// Kernel 2: out[i][c] = b[c] + dis_i * sum_{j in row i} dis_j * z[j][c]
// (self loop is already in the list). One wave per row, 4 rows per block.
// UNCHANGED from round 3 for attribution.
// ---------------------------------------------------------------------------
__global__ __launch_bounds__(256) void gcn_agg(const int* __restrict__ deg,
                                               const float* __restrict__ dis,
                                               const uint16_t* __restrict__ list,
                                               const uint16_t* __restrict__ z16,
                                               const float* __restrict__ bias,
                                               float* __restrict__ out) {
    int row  = blockIdx.x * 4 + (threadIdx.x >> 6);
    int lane = threadIdx.x & 63;
    int n = min(deg[row], MAXDEG);

    const uint16_t* lrow = list + (size_t)row * MAXDEG;
    int j0 = (lane < n)      ? lrow[lane]      : 0;
    int j1 = (64 + lane < n) ? lrow[64 + lane] : 0;
    float d0 = dis[j0];
    float d1 = dis[j1];

    const uint32_t* zu = (const uint32_t*)z16;
    float a0 = 0.f, a1 = 0.f, c0 = 0.f, c1 = 0.f;
    int n0 = min(n, 64);
    int m = 0;
    for (; m + 2 <= n0; m += 2) {
        int   ja = __shfl(j0, m, 64);     float da = __shfl(d0, m, 64);
        int   jb = __shfl(j0, m + 1, 64); float db = __shfl(d0, m + 1, 64);
        uint32_t ua = zu[(size_t)ja * 64 + lane];   // coalesced 256 B
        uint32_t ub = zu[(size_t)jb * 64 + lane];
        a0 += da * bf2f(ua & 0xffffu);
        a1 += da * bf2f(ua >> 16);
        c0 += db * bf2f(ub & 0xffffu);
        c1 += db * bf2f(ub >> 16);
    }
    if (m < n0) {
        int   ja = __shfl(j0, m, 64); float da = __shfl(d0, m, 64);
        uint32_t ua = zu[(size_t)ja * 64 + lane];
        a0 += da * bf2f(ua & 0xffffu);
        a1 += da * bf2f(ua >> 16);
    }
    for (int m2 = 64; m2 < n; m2++) {               // rare (deg > 64)
        int   jb = __shfl(j1, m2 - 64, 64); float db = __shfl(d1, m2 - 64, 64);
        uint32_t ub = zu[(size_t)jb * 64 + lane];
        c0 += db * bf2f(ub & 0xffffu);
        c1 += db * bf2f(ub >> 16);
    }
    a0 += c0; a1 += c1;

    float di = dis[row];
    float2 bv = ((const float2*)bias)[lane];
    float2 o;
    o.x = bv.x + di * a0;
    o.y = bv.y + di * a1;
    ((float2*)out)[(size_t)row * 64 + lane] = o;
}

// ---------------------------------------------------------------------------
extern "C" void kernel_launch(void* const* d_in, const int* in_sizes, int n_in,
                              void* d_out, int out_size, void* d_ws, size_t ws_size,
                              hipStream_t stream) {
    const float* x  = (const float*)d_in[0];
    const int*   ei = (const int*)d_in[1];
    const float* W  = (const float*)d_in[2];
    const float* b  = (const float*)d_in[3];
    float* out = (float*)d_out;

    int E = in_sizes[1] / 2;

    float*    dis  = (float*)   d_ws;
    int*      deg  = (int*)     ((char*)d_ws + OFF_DEG);
    uint16_t* list = (uint16_t*)((char*)d_ws + OFF_LIST);
    uint16_t* z16  = (uint16_t*)((char*)d_ws + OFF_Z16);

    // adjacency build+extract (LDS bitmask, no global atomics)  ||  x@W^T
    gcn_build<<<MB_BLOCKS + XW_BLOCKS, 512, 0, stream>>>(ei, E, x, W, z16, dis, deg, list);

    gcn_agg<<<N_NODES / 4, 256, 0, stream>>>(deg, dis, list, z16, b, out);
}

// Round 5
// 92.542 us; speedup vs baseline: 1.1465x; 1.1465x over previous
//
#include <hip/hip_runtime.h>
#include <cstdint>

#define N_NODES 8192
#define DIN 128
#define DOUT 128
#define MAXDEG 128                               // Poisson(32): P(deg>128) ~ 1e-18
#define EPS 1e-8f

#define NB 256                                   // buckets == build blocks
#define BROWS 32                                 // adjacency rows per bucket/build block
#define WPR 256                                  // u32 words per adjacency row (8192/32)
#define SCB 128                                  // scatter blocks
#define BCAP 64                                  // slots per (scatter block, bucket); mean 8
#define XWB 256                                  // xw blocks
#define XW_ROWS 32                               // rows per xw block

// workspace layout (bytes):
// [dis 32K][deg 32K][list 2M][z16 2M][cnt 128K][bucket 8M]
#define OFF_DEG   (N_NODES * 4)
#define OFF_LIST  (OFF_DEG + N_NODES * 4)
#define OFF_Z16   (OFF_LIST + N_NODES * MAXDEG * 2)
#define OFF_CNT   (OFF_Z16 + N_NODES * DOUT * 2)
#define OFF_BUCK  (OFF_CNT + SCB * NB * 4)

static __device__ __forceinline__ uint16_t f2bf(float f) {
    uint32_t u = __float_as_uint(f);
    return (uint16_t)((u + 0x7fffu + ((u >> 16) & 1u)) >> 16);   // RNE
}
static __device__ __forceinline__ float bf2f(uint32_t bits16) {
    return __uint_as_float(bits16 << 16);
}

// ---------------------------------------------------------------------------
// Kernel 1: blocks [0,128): edge bucket-scatter. Each block owns E/128 edges
//   (exactly 1 int4-pair per thread at E=262144 — single load round, no
//   pipelining needed). Rank within (block,bucket) comes from an LDS
//   returning atomicAdd; each (block,bucket) has a statically reserved
//   64-slot region -> NO global atomics, NO counter initialization.
//   Packed edge: (src&31)<<13 | dst (18 bits).
// blocks [128,384): z16 = bf16(x @ W^T), 32 rows per block (4 column-teams).
// ---------------------------------------------------------------------------
__global__ __launch_bounds__(512) void gcn_scatter_xw(const int* __restrict__ ei, int E,
                                                      const float* __restrict__ x,
                                                      const float* __restrict__ W,
                                                      uint16_t* __restrict__ z16,
                                                      uint32_t* __restrict__ cnt,
                                                      uint32_t* __restrict__ bucket) {
    __shared__ uint32_t shbuf[XW_ROWS * DIN + NB];   // 16 KB xw floats | 1 KB hist
    int t = threadIdx.x;

    if ((int)blockIdx.x < SCB) {
        // ---------------- scatter role ----------------
        int sb = blockIdx.x;
        uint32_t* hist = shbuf;                      // [NB]
        if (t < NB) hist[t] = 0;
        __syncthreads();

        const int4* s4 = (const int4*)ei;
        const int4* d4 = (const int4*)(ei + E);
        int nIter = E >> 2;

#define SC1(ss, dd) do { unsigned b_ = ((unsigned)(ss)) >> 5;                              \
            unsigned r_ = atomicAdd(&hist[b_], 1u);                                        \
            if (r_ < BCAP) bucket[(b_ << 13) + (sb << 6) + r_] =                           \
                (((unsigned)(ss) & 31u) << 13) | (unsigned)(dd); } while (0)

        for (int g = sb * 512 + t; g < nIter; g += SCB * 512) {   // exactly 1 iter here
            int4 vs = s4[g], vd = d4[g];
            SC1(vs.x, vd.x); SC1(vs.y, vd.y); SC1(vs.z, vd.z); SC1(vs.w, vd.w);
        }
        if (sb == 0) {                                            // scalar tail (E % 4)
            for (int i = (nIter << 2) + t; i < E; i += 512) {
                int ss = ei[i], dd = ei[E + i];
                SC1(ss, dd);
            }
        }
#undef SC1
        __syncthreads();
        if (t < NB) cnt[(sb << 8) + t] = hist[t];
        return;
    }

    // ---------------- xw role: 4 column-teams of 128; team does 8 rows ----
    int bb = blockIdx.x - SCB;
    int col = t & 127;
    int team = t >> 7;                               // 0..3
    int row0 = bb * XW_ROWS + team * 8;
    float* xl = (float*)shbuf;                       // [32][128] = 16 KB

    for (int rr = 0; rr < 8; rr++)
        xl[(team * 8 + rr) * DIN + col] = x[(size_t)(row0 + rr) * DIN + col];
    __syncthreads();

    float acc[8];
#pragma unroll
    for (int rr = 0; rr < 8; rr++) acc[rr] = 0.f;

    const float* wrow = W + (size_t)col * DIN;
    for (int d = 0; d < DIN; d += 4) {
        float4 wv = *(const float4*)(wrow + d);
#pragma unroll
        for (int rr = 0; rr < 8; rr++) {
            const float* xr = &xl[(team * 8 + rr) * DIN + d];   // wave-uniform broadcast
            acc[rr] += xr[0] * wv.x + xr[1] * wv.y + xr[2] * wv.z + xr[3] * wv.w;
        }
    }
#pragma unroll
    for (int rr = 0; rr < 8; rr++)
        z16[(size_t)(row0 + rr) * DOUT + col] = f2bf(acc[rr]);
}

// ---------------------------------------------------------------------------
// Kernel 2: per-bucket adjacency build + extract. Block mb owns rows
//   [mb*32, mb*32+32) as a 32 KB LDS bitmask (diag pre-folded into init).
//   Reads its 32 KB bucket slice with 4 independent unconditional uint4
//   loads per thread (validity checked against cnt), LDS atomicOr dedup,
//   then popcount + wave scan -> deg/dis/list.
// ---------------------------------------------------------------------------
__global__ __launch_bounds__(512) void gcn_build(const uint32_t* __restrict__ cnt,
                                                 const uint32_t* __restrict__ bucket,
                                                 float* __restrict__ dis,
                                                 int* __restrict__ deg,
                                                 uint16_t* __restrict__ list) {
    __shared__ uint32_t lm[BROWS * WPR];             // 32 KB
    __shared__ uint32_t cl[SCB];
    int t = threadIdx.x;
    int mb = blockIdx.x;
    int r0 = mb * BROWS;

    // init: zero + diagonal. word w: r=w>>8 (<32), wir=w&255.
    // diag word-in-row of row (r0+r) is (r0+r)>>5 == mb; bit is (r0+r)&31 == r.
    for (int w4 = t; w4 < BROWS * WPR / 4; w4 += 512) {
        uint32_t w0 = w4 * 4;
        uint32_t vals[4];
#pragma unroll
        for (int k = 0; k < 4; k++) {
            uint32_t w = w0 + k;
            uint32_t r = w >> 8;
            uint32_t wir = w & 255u;
            vals[k] = (wir == (uint32_t)mb) ? (1u << r) : 0u;
        }
        ((uint4*)lm)[w4] = make_uint4(vals[0], vals[1], vals[2], vals[3]);
    }
    if (t < SCB) cl[t] = min(cnt[(t << 8) + mb], (uint32_t)BCAP);
    __syncthreads();

    // gather bucket slice: 8192 u32 = 2048 uint4; 4 independent loads/thread
    const uint4* bk4 = (const uint4*)(bucket + ((size_t)mb << 13));
#pragma unroll
    for (int j = 0; j < 4; j++) {
        int i4 = t + j * 512;
        uint4 u = bk4[i4];                           // unconditional -> pipelined
        uint32_t uu[4] = {u.x, u.y, u.z, u.w};
        int ibase = i4 * 4;
#pragma unroll
        for (int c2 = 0; c2 < 4; c2++) {
            int i = ibase + c2;
            if ((uint32_t)(i & 63) < cl[i >> 6]) {
                uint32_t p = uu[c2];
                int row = p >> 13;
                int dst = p & 8191;
                atomicOr(&lm[row * WPR + (dst >> 5)], 1u << (dst & 31));
            }
        }
    }
    __syncthreads();

    // extract: 8 waves, 4 rows per wave. popcount + wave prefix scan
    int wave = t >> 6, lane = t & 63;
    for (int rr = 0; rr < BROWS / 8; rr++) {
        int r = wave * (BROWS / 8) + rr;
        int row = r0 + r;
        uint4 w = ((const uint4*)(lm + r * WPR))[lane];   // words 4*lane..4*lane+3
        uint32_t wa[4] = {w.x, w.y, w.z, w.w};
        int c = __popc(w.x) + __popc(w.y) + __popc(w.z) + __popc(w.w);

        int sum = c;                                 // inclusive wave scan (width 64)
        for (int off = 1; off < 64; off <<= 1) {
            int v = __shfl_up(sum, off, 64);
            if (lane >= off) sum += v;
        }
        int excl = sum - c;
        if (lane == 63) {
            deg[row] = sum;
            dis[row] = rsqrtf((float)sum + EPS);
        }

        uint16_t* lrow = list + (size_t)row * MAXDEG;
        int bbase = lane * 128;                      // first bit index of this lane
        int pos = excl;
#pragma unroll
        for (int k = 0; k < 4; k++) {
            uint32_t m = wa[k];
            while (m) {
                int b = __ffs(m) - 1;
                m &= m - 1;
                if (pos < MAXDEG) lrow[pos] = (uint16_t)(bbase + k * 32 + b);
                pos++;
            }
        }
    }
}

// ---------------------------------------------------------------------------
// Kernel 3: out[i][c] = b[c] + dis_i * sum_{j in row i} dis_j * z[j][c]
// (self loop is already in the list). One wave per row, 4 rows per block.
// UNCHANGED (R3 version, passed twice) for attribution.
// ---------------------------------------------------------------------------
__global__ __launch_bounds__(256) void gcn_agg(const int* __restrict__ deg,
                                               const float* __restrict__ dis,
                                               const uint16_t* __restrict__ list,
                                               const uint16_t* __restrict__ z16,
                                               const float* __restrict__ bias,
                                               float* __restrict__ out) {
    int row  = blockIdx.x * 4 + (threadIdx.x >> 6);
    int lane = threadIdx.x & 63;
    int n = min(deg[row], MAXDEG);

    const uint16_t* lrow = list + (size_t)row * MAXDEG;
    int j0 = (lane < n)      ? lrow[lane]      : 0;
    int j1 = (64 + lane < n) ? lrow[64 + lane] : 0;
    float d0 = dis[j0];
    float d1 = dis[j1];

    const uint32_t* zu = (const uint32_t*)z16;
    float a0 = 0.f, a1 = 0.f, c0 = 0.f, c1 = 0.f;
    int n0 = min(n, 64);
    int m = 0;
    for (; m + 2 <= n0; m += 2) {
        int   ja = __shfl(j0, m, 64);     float da = __shfl(d0, m, 64);
        int   jb = __shfl(j0, m + 1, 64); float db = __shfl(d0, m + 1, 64);
        uint32_t ua = zu[(size_t)ja * 64 + lane];   // coalesced 256 B
        uint32_t ub = zu[(size_t)jb * 64 + lane];
        a0 += da * bf2f(ua & 0xffffu);
        a1 += da * bf2f(ua >> 16);
        c0 += db * bf2f(ub & 0xffffu);
        c1 += db * bf2f(ub >> 16);
    }
    if (m < n0) {
        int   ja = __shfl(j0, m, 64); float da = __shfl(d0, m, 64);
        uint32_t ua = zu[(size_t)ja * 64 + lane];
        a0 += da * bf2f(ua & 0xffffu);
        a1 += da * bf2f(ua >> 16);
    }
    for (int m2 = 64; m2 < n; m2++) {               // rare (deg > 64)
        int   jb = __shfl(j1, m2 - 64, 64); float db = __shfl(d1, m2 - 64, 64);
        uint32_t ub = zu[(size_t)jb * 64 + lane];
        c0 += db * bf2f(ub & 0xffffu);
        c1 += db * bf2f(ub >> 16);
    }
    a0 += c0; a1 += c1;

    float di = dis[row];
    float2 bv = ((const float2*)bias)[lane];
    float2 o;
    o.x = bv.x + di * a0;
    o.y = bv.y + di * a1;
    ((float2*)out)[(size_t)row * 64 + lane] = o;
}

// ---------------------------------------------------------------------------
extern "C" void kernel_launch(void* const* d_in, const int* in_sizes, int n_in,
                              void* d_out, int out_size, void* d_ws, size_t ws_size,
                              hipStream_t stream) {
    const float* x  = (const float*)d_in[0];
    const int*   ei = (const int*)d_in[1];
    const float* W  = (const float*)d_in[2];
    const float* b  = (const float*)d_in[3];
    float* out = (float*)d_out;

    int E = in_sizes[1] / 2;

    float*    dis    = (float*)   d_ws;
    int*      deg    = (int*)     ((char*)d_ws + OFF_DEG);
    uint16_t* list   = (uint16_t*)((char*)d_ws + OFF_LIST);
    uint16_t* z16    = (uint16_t*)((char*)d_ws + OFF_Z16);
    uint32_t* cnt    = (uint32_t*)((char*)d_ws + OFF_CNT);
    uint32_t* bucket = (uint32_t*)((char*)d_ws + OFF_BUCK);

    // edge bucket-scatter (no global atomics, no init pass)  ||  x@W^T
    gcn_scatter_xw<<<SCB + XWB, 512, 0, stream>>>(ei, E, x, W, z16, cnt, bucket);

    // per-bucket LDS bitmask build + extract
    gcn_build<<<NB, 512, 0, stream>>>(cnt, bucket, dis, deg, list);

    gcn_agg<<<N_NODES / 4, 256, 0, stream>>>(deg, dis, list, z16, b, out);
}